// Round 1
// baseline (78.401 us; speedup 1.0000x reference)
//
#include <hip/hip_runtime.h>
#include <hip/hip_bf16.h>

typedef __attribute__((ext_vector_type(8))) short bf16x8;
typedef __attribute__((ext_vector_type(4))) float f32x4;

constexpr int P = 8192, C = 8192, D = 256;
constexpr int BM = 128, BN = 128, BK = 32;

__device__ __forceinline__ void gload_lds16(const void* g, void* l) {
    __builtin_amdgcn_global_load_lds((const __attribute__((address_space(1))) void*)g,
                                     (__attribute__((address_space(3))) void*)l, 16, 0, 0);
}

// f32 row -> bf16 row + inv norm (1/sqrt(sum sq)) per row. One block per row.
__global__ __launch_bounds__(256) void prep_kernel(const float* __restrict__ feat,
                                                   __hip_bfloat16* __restrict__ fb,
                                                   float* __restrict__ inv) {
    const int row = blockIdx.x;
    const int t = threadIdx.x;            // D == 256 == blockDim
    const size_t idx = (size_t)row * D + t;
    float v = feat[idx];
    fb[idx] = __float2bfloat16(v);
    float ss = v * v;
#pragma unroll
    for (int off = 32; off; off >>= 1) ss += __shfl_xor(ss, off, 64);
    __shared__ float red[4];
    const int lane = t & 63, wv = t >> 6;
    if (lane == 0) red[wv] = ss;
    __syncthreads();
    if (t == 0) inv[row] = 1.0f / sqrtf(red[0] + red[1] + red[2] + red[3]);
}

// 128x128 output tile per block, 4 waves (2x2), each wave 64x64 via 4x4
// mfma_f32_16x16x32_bf16 fragments. NT GEMM: both A and B row-major [*,D],
// out[p][c] = dot(prev[p], cur[c]). Fused cosine + BCE epilogue, per-block
// partial sum (no atomics -> deterministic).
__global__ __launch_bounds__(256) void gemm_bce_kernel(
    const __hip_bfloat16* __restrict__ Ab, const __hip_bfloat16* __restrict__ Bb,
    const float* __restrict__ invp, const float* __restrict__ invc,
    const int* __restrict__ pids, const int* __restrict__ cids,
    float* __restrict__ partial) {
    __shared__ short sA[BM * BK];
    __shared__ short sB[BN * BK];

    const int tid = threadIdx.x;
    const int lane = tid & 63;
    const int wv = tid >> 6;
    const int wr = wv >> 1, wc = wv & 1;
    const int pblock = blockIdx.y * BM;
    const int cblock = blockIdx.x * BN;

    f32x4 acc[4][4] = {};

    const int srow = lane >> 2;          // row within 16-row staging chunk
    const int skoff = (lane & 3) * 8;    // bf16 k-offset within BK

    for (int k0 = 0; k0 < D; k0 += BK) {
#pragma unroll
        for (int i = 0; i < 2; ++i) {
            const int q = wv * 2 + i;    // 8 chunks of 16 rows each
            gload_lds16(Ab + (size_t)(pblock + q * 16 + srow) * D + k0 + skoff, &sA[q * 512]);
            gload_lds16(Bb + (size_t)(cblock + q * 16 + srow) * D + k0 + skoff, &sB[q * 512]);
        }
        __syncthreads();
        bf16x8 af[4], bfr[4];
        const int kg = (lane >> 4) * 8;
#pragma unroll
        for (int i = 0; i < 4; ++i)
            af[i] = *(const bf16x8*)&sA[(wr * 64 + i * 16 + (lane & 15)) * BK + kg];
#pragma unroll
        for (int j = 0; j < 4; ++j)
            bfr[j] = *(const bf16x8*)&sB[(wc * 64 + j * 16 + (lane & 15)) * BK + kg];
#pragma unroll
        for (int i = 0; i < 4; ++i)
#pragma unroll
            for (int j = 0; j < 4; ++j)
                acc[i][j] = __builtin_amdgcn_mfma_f32_16x16x32_bf16(af[i], bfr[j], acc[i][j], 0, 0, 0);
        __syncthreads();
    }

    // Epilogue: C/D layout col=lane&15, row=(lane>>4)*4+reg (m89-verified).
    const int p0 = pblock + wr * 64;
    const int c0 = cblock + wc * 64;
    float invp_r[16]; int pid_r[16];
#pragma unroll
    for (int i = 0; i < 4; ++i)
#pragma unroll
        for (int r = 0; r < 4; ++r) {
            const int p = p0 + i * 16 + (lane >> 4) * 4 + r;
            invp_r[i * 4 + r] = invp[p];
            pid_r[i * 4 + r] = pids[p];
        }
    float invc_r[4]; int cid_r[4];
#pragma unroll
    for (int j = 0; j < 4; ++j) {
        const int c = c0 + j * 16 + (lane & 15);
        invc_r[j] = invc[c];
        cid_r[j] = cids[c];
    }

    constexpr float L2E = 1.4426950408889634f;
    constexpr float LN2 = 0.69314718055994531f;
    float lsum = 0.f;
#pragma unroll
    for (int i = 0; i < 4; ++i)
#pragma unroll
        for (int j = 0; j < 4; ++j)
#pragma unroll
            for (int r = 0; r < 4; ++r) {
                const float x = acc[i][j][r] * invp_r[i * 4 + r] * invc_r[j];
                // y==1: max(x,0)-x = max(-x,0); y==0: max(x,0). |s| == |x|.
                const float s = (pid_r[i * 4 + r] == cid_r[j]) ? -x : x;
                const float ax = fabsf(x);
                const float t = __builtin_amdgcn_exp2f(-L2E * ax);
                lsum += fmaxf(s, 0.f) + LN2 * __builtin_amdgcn_logf(1.f + t);
            }

#pragma unroll
    for (int off = 32; off; off >>= 1) lsum += __shfl_xor(lsum, off, 64);
    __shared__ float wsum[4];
    if (lane == 0) wsum[wv] = lsum;
    __syncthreads();
    if (tid == 0) partial[blockIdx.y * gridDim.x + blockIdx.x] = wsum[0] + wsum[1] + wsum[2] + wsum[3];
}

// Deterministic final reduction of 4096 block partials (fixed order, double).
__global__ __launch_bounds__(256) void reduce_kernel(const float* __restrict__ part,
                                                     float* __restrict__ out) {
    const int tid = threadIdx.x;
    double s = 0.0;
    for (int i = tid; i < 4096; i += 256) s += (double)part[i];
#pragma unroll
    for (int off = 32; off; off >>= 1) s += __shfl_xor(s, off, 64);
    __shared__ double red[4];
    const int lane = tid & 63, wv = tid >> 6;
    if (lane == 0) red[wv] = s;
    __syncthreads();
    if (tid == 0) out[0] = (float)((red[0] + red[1] + red[2] + red[3]) * (1.0 / ((double)P * (double)C)));
}

extern "C" void kernel_launch(void* const* d_in, const int* in_sizes, int n_in,
                              void* d_out, int out_size, void* d_ws, size_t ws_size,
                              hipStream_t stream) {
    const float* prev_feat = (const float*)d_in[0];
    const float* cur_feat  = (const float*)d_in[1];
    const int* prev_ids    = (const int*)d_in[2];
    const int* cur_ids     = (const int*)d_in[3];
    float* out = (float*)d_out;

    char* ws = (char*)d_ws;
    __hip_bfloat16* prevb = (__hip_bfloat16*)ws;                          // 4 MB
    __hip_bfloat16* curb  = (__hip_bfloat16*)(ws + (size_t)P * D * 2);    // 4 MB
    float* invp = (float*)(ws + (size_t)(P + C) * D * 2);                 // 32 KB
    float* invc = invp + P;                                               // 32 KB
    float* partial = invc + C;                                            // 16 KB

    prep_kernel<<<P, 256, 0, stream>>>(prev_feat, prevb, invp);
    prep_kernel<<<C, 256, 0, stream>>>(cur_feat, curb, invc);
    dim3 grid(C / BN, P / BM);
    gemm_bce_kernel<<<grid, 256, 0, stream>>>(prevb, curb, invp, invc, prev_ids, cur_ids, partial);
    reduce_kernel<<<1, 256, 0, stream>>>(partial, out);
}

// Round 2
// 66.901 us; speedup vs baseline: 1.1719x; 1.1719x over previous
//
#include <hip/hip_runtime.h>
#include <hip/hip_bf16.h>

typedef __attribute__((ext_vector_type(8))) short bf16x8;
typedef __attribute__((ext_vector_type(4))) float f32x4;

constexpr int P = 8192, C = 8192, D = 256;
constexpr int BM = 128, BN = 128, BK = 32;

__device__ __forceinline__ void gload_lds16(const void* g, void* l) {
    __builtin_amdgcn_global_load_lds((const __attribute__((address_space(1))) void*)g,
                                     (__attribute__((address_space(3))) void*)l, 16, 0, 0);
}

__device__ __forceinline__ unsigned short bfbits(float f) {
    __hip_bfloat16 h = __float2bfloat16(f);
    return __builtin_bit_cast(unsigned short, h);
}

// Normalize rows to unit L2 norm, store bf16. One wave per row, float4 loads.
// rows [0,P) -> prevb, [P, P+C) -> curb.
__global__ __launch_bounds__(256) void prep_kernel(const float* __restrict__ prev,
                                                   const float* __restrict__ cur,
                                                   unsigned short* __restrict__ prevb,
                                                   unsigned short* __restrict__ curb) {
    const int lane = threadIdx.x & 63;
    const int wv = threadIdx.x >> 6;
    const int row = blockIdx.x * 4 + wv;
    const float* src;
    unsigned short* dst;
    int r;
    if (row < P) { src = prev; dst = prevb; r = row; }
    else         { src = cur;  dst = curb;  r = row - P; }
    const float4 v = *(const float4*)(src + (size_t)r * D + lane * 4);
    float ss = v.x * v.x + v.y * v.y + v.z * v.z + v.w * v.w;
#pragma unroll
    for (int off = 32; off; off >>= 1) ss += __shfl_xor(ss, off, 64);
    const float inv = 1.0f / sqrtf(ss);   // norms ~16; eps=1e-6 unreachable
    ushort4 o;
    o.x = bfbits(v.x * inv);
    o.y = bfbits(v.y * inv);
    o.z = bfbits(v.z * inv);
    o.w = bfbits(v.w * inv);
    *(ushort4*)(dst + (size_t)r * D + lane * 4) = o;
}

// 128x128 tile, 4 waves (2x2), 4x4 x mfma_f32_16x16x32_bf16 per wave.
// Double-buffered LDS, 2-phase: stage(t+1) issued before compute(t), single
// barrier per K-step (its implicit vmcnt(0) drain sits after the MFMA window).
// Inputs pre-normalized -> acc IS the cosine. Fused BCE via even-poly softplus:
//   elem = x*(0.5 - y) + ln2 + t*q(t), t=x^2  (ln2 folded into reduce kernel)
__global__ __launch_bounds__(256) void gemm_bce_kernel(
    const unsigned short* __restrict__ Ab, const unsigned short* __restrict__ Bb,
    const int* __restrict__ pids, const int* __restrict__ cids,
    float* __restrict__ partial) {
    __shared__ short sA[2][BM * BK];
    __shared__ short sB[2][BN * BK];

    const int tid = threadIdx.x;
    const int lane = tid & 63;
    const int wv = tid >> 6;
    const int wr = wv >> 1, wc = wv & 1;
    const int pblock = blockIdx.y * BM;
    const int cblock = blockIdx.x * BN;

    f32x4 acc[4][4] = {};

    const int srow = lane >> 2;          // row within a 16-row staging chunk
    const int skoff = (lane & 3) * 8;    // bf16 k-offset (16B granules)

    auto stage = [&](int buf, int k0) {
#pragma unroll
        for (int i = 0; i < 2; ++i) {
            const int q = wv * 2 + i;    // 8 chunks of 16 rows
            gload_lds16(Ab + (size_t)(pblock + q * 16 + srow) * D + k0 + skoff, &sA[buf][q * 512]);
            gload_lds16(Bb + (size_t)(cblock + q * 16 + srow) * D + k0 + skoff, &sB[buf][q * 512]);
        }
    };

    stage(0, 0);
    __syncthreads();                      // drains vmcnt(0) before first read

    const int kg = (lane >> 4) * 8;
    const int arow = wr * 64 + (lane & 15);
    const int brow = wc * 64 + (lane & 15);

#pragma unroll
    for (int t = 0; t < 8; ++t) {
        const int cur = t & 1;
        if (t < 7) stage(cur ^ 1, (t + 1) * BK);   // issue BEFORE compute
        bf16x8 af[4], bfr[4];
#pragma unroll
        for (int i = 0; i < 4; ++i)
            af[i] = *(const bf16x8*)&sA[cur][(arow + i * 16) * BK + kg];
#pragma unroll
        for (int j = 0; j < 4; ++j)
            bfr[j] = *(const bf16x8*)&sB[cur][(brow + j * 16) * BK + kg];
#pragma unroll
        for (int i = 0; i < 4; ++i)
#pragma unroll
            for (int j = 0; j < 4; ++j)
                acc[i][j] = __builtin_amdgcn_mfma_f32_16x16x32_bf16(af[i], bfr[j], acc[i][j], 0, 0, 0);
        __syncthreads();                  // one barrier per step; dbuf makes it safe
    }

    // Epilogue. C/D layout: col=lane&15, row=(lane>>4)*4+reg (m89-verified).
    const int p0 = pblock + wr * 64 + (lane >> 4) * 4;
    const int c0 = cblock + wc * 64 + (lane & 15);
    int pid_r[16];
#pragma unroll
    for (int i = 0; i < 4; ++i)
#pragma unroll
        for (int r = 0; r < 4; ++r) pid_r[i * 4 + r] = pids[p0 + i * 16 + r];
    int cid_r[4];
#pragma unroll
    for (int j = 0; j < 4; ++j) cid_r[j] = cids[c0 + j * 16];

    // ln(2cosh(x/2)) - ln2 = t/8 - t^2/192 + t^3/2880 - 17t^4/645120, t=x^2
    constexpr float C1 = 0.125f, C2 = -5.2083333e-3f, C3 = 3.4722222e-4f, C4 = -2.6354832e-5f;
    float sh = 0.f, sx = 0.f;
#pragma unroll
    for (int i = 0; i < 4; ++i)
#pragma unroll
        for (int j = 0; j < 4; ++j)
#pragma unroll
            for (int r = 0; r < 4; ++r) {
                const float x = acc[i][j][r];
                const float t2 = x * x;
                float q = __builtin_fmaf(t2, C4, C3);
                q = __builtin_fmaf(t2, q, C2);
                q = __builtin_fmaf(t2, q, C1);
                sh = __builtin_fmaf(t2, q, sh);
                const float cc = (pid_r[i * 4 + r] == cid_r[j]) ? -0.5f : 0.5f;
                sx = __builtin_fmaf(x, cc, sx);
            }
    float lsum = sh + sx;

#pragma unroll
    for (int off = 32; off; off >>= 1) lsum += __shfl_xor(lsum, off, 64);
    __shared__ float wsum[4];
    if (lane == 0) wsum[wv] = lsum;
    __syncthreads();
    if (tid == 0) partial[blockIdx.y * gridDim.x + blockIdx.x] = wsum[0] + wsum[1] + wsum[2] + wsum[3];
}

// Deterministic final reduction; adds the analytically-folded ln2 term.
__global__ __launch_bounds__(256) void reduce_kernel(const float* __restrict__ part,
                                                     float* __restrict__ out) {
    const int tid = threadIdx.x;
    double s = 0.0;
    for (int i = tid; i < 4096; i += 256) s += (double)part[i];
#pragma unroll
    for (int off = 32; off; off >>= 1) s += __shfl_xor(s, off, 64);
    __shared__ double red[4];
    const int lane = tid & 63, wv = tid >> 6;
    if (lane == 0) red[wv] = s;
    __syncthreads();
    if (tid == 0)
        out[0] = (float)((red[0] + red[1] + red[2] + red[3]) * (1.0 / ((double)P * (double)C))
                         + 0.69314718055994531);
}

extern "C" void kernel_launch(void* const* d_in, const int* in_sizes, int n_in,
                              void* d_out, int out_size, void* d_ws, size_t ws_size,
                              hipStream_t stream) {
    const float* prev_feat = (const float*)d_in[0];
    const float* cur_feat  = (const float*)d_in[1];
    const int* prev_ids    = (const int*)d_in[2];
    const int* cur_ids     = (const int*)d_in[3];
    float* out = (float*)d_out;

    char* ws = (char*)d_ws;
    unsigned short* prevb = (unsigned short*)ws;                          // 4 MB
    unsigned short* curb  = (unsigned short*)(ws + (size_t)P * D * 2);    // 4 MB
    float* partial = (float*)(ws + (size_t)(P + C) * D * 2);              // 16 KB

    prep_kernel<<<(P + C) / 4, 256, 0, stream>>>(prev_feat, cur_feat, prevb, curb);
    dim3 grid(C / BN, P / BM);
    gemm_bce_kernel<<<grid, 256, 0, stream>>>(prevb, curb, prev_ids, cur_ids, partial);
    reduce_kernel<<<1, 256, 0, stream>>>(partial, out);
}

// Round 3
// 60.950 us; speedup vs baseline: 1.2863x; 1.0977x over previous
//
#include <hip/hip_runtime.h>
#include <hip/hip_bf16.h>

typedef __attribute__((ext_vector_type(8))) short bf16x8;
typedef __attribute__((ext_vector_type(4))) float f32x4;

constexpr int P = 8192, C = 8192, D = 256;
constexpr int BM = 128;   // rows per block (A slab, held in registers)
constexpr int BN = 128;   // cols per N-tile
constexpr int BK = 32;
constexpr int NT = 8;     // N-tiles per block
constexpr int KS = D / BK;  // 8 K-steps

__device__ __forceinline__ void gload_lds16(const void* g, void* l) {
    __builtin_amdgcn_global_load_lds((const __attribute__((address_space(1))) void*)g,
                                     (__attribute__((address_space(3))) void*)l, 16, 0, 0);
}

__device__ __forceinline__ unsigned short bfbits(float f) {
    __hip_bfloat16 h = __float2bfloat16(f);
    return __builtin_bit_cast(unsigned short, h);
}

// Normalize rows to unit L2 norm, store bf16. One wave per row, float4 loads.
__global__ __launch_bounds__(256) void prep_kernel(const float* __restrict__ prev,
                                                   const float* __restrict__ cur,
                                                   unsigned short* __restrict__ prevb,
                                                   unsigned short* __restrict__ curb) {
    const int lane = threadIdx.x & 63;
    const int wv = threadIdx.x >> 6;
    const int row = blockIdx.x * 4 + wv;
    const float* src;
    unsigned short* dst;
    int r;
    if (row < P) { src = prev; dst = prevb; r = row; }
    else         { src = cur;  dst = curb;  r = row - P; }
    const float4 v = *(const float4*)(src + (size_t)r * D + lane * 4);
    float ss = v.x * v.x + v.y * v.y + v.z * v.z + v.w * v.w;
#pragma unroll
    for (int off = 32; off; off >>= 1) ss += __shfl_xor(ss, off, 64);
    const float inv = 1.0f / sqrtf(ss);   // norms ~16; eps=1e-6 unreachable
    ushort4 o;
    o.x = bfbits(v.x * inv);
    o.y = bfbits(v.y * inv);
    o.z = bfbits(v.z * inv);
    o.w = bfbits(v.w * inv);
    *(ushort4*)(dst + (size_t)r * D + lane * 4) = o;
}

// Persistent-A GEMM: each block owns 128 rows x full K in REGISTERS (32 bf16x8
// per thread), loops over 8 N-tiles of 128 cols. Only B streams through LDS
// (double-buffered, XOR-swizzled granules -> conflict-free ds_read_b128); the
// B pipeline runs continuously across N-tile boundaries. 4 waves (2x2), each
// 64x64 per tile via 4x4 mfma_f32_16x16x32_bf16. Fused BCE epilogue per tile
// (pure VALU, no barrier); one block reduction at the end.
__global__ __launch_bounds__(256, 2) void gemm_bce_kernel(
    const unsigned short* __restrict__ Ab, const unsigned short* __restrict__ Bb,
    const int* __restrict__ pids, const int* __restrict__ cids,
    float* __restrict__ partial) {
    __shared__ short sB[2][BN * BK];   // 2 x 8 KB

    const int tid = threadIdx.x;
    const int lane = tid & 63;
    const int wv = tid >> 6;
    const int wr = wv >> 1, wc = wv & 1;
    const int pblock = blockIdx.y * BM;
    const int cbase = blockIdx.x * (BN * NT);

    const int kg = (lane >> 4) * 8;       // k-granule offset within a K-step
    const int arow0 = pblock + wr * 64 + (lane & 15);

    // ---- A slab -> registers (held for the whole kernel) ----
    bf16x8 a[4][8];
#pragma unroll
    for (int m = 0; m < 4; ++m)
#pragma unroll
        for (int ks = 0; ks < KS; ++ks)
            a[m][ks] = *(const bf16x8*)(Ab + (size_t)(arow0 + m * 16) * D + ks * BK + kg);

    int pid_r[16];
#pragma unroll
    for (int m = 0; m < 4; ++m)
#pragma unroll
        for (int r = 0; r < 4; ++r)
            pid_r[m * 4 + r] = pids[pblock + wr * 64 + m * 16 + (lane >> 4) * 4 + r];

    // ---- B staging (swizzled source granule; LDS written linearly) ----
    const int srow = lane >> 2;                         // row within 16-row chunk
    const int sg = (lane & 3) ^ ((lane >> 3) & 3);      // inverse-swizzled granule
    auto stageB = [&](int buf, int ntile, int k0) {
#pragma unroll
        for (int i = 0; i < 2; ++i) {
            const int q = wv * 2 + i;                   // 8 chunks of 16 rows
            gload_lds16(Bb + (size_t)(cbase + ntile * BN + q * 16 + srow) * D + k0 + sg * 8,
                        &sB[buf][q * 512]);
        }
    };

    stageB(0, 0, 0);
    __syncthreads();

    const int brow = wc * 64 + (lane & 15);
    const int rg = ((lane & 15) >> 1) & 3;              // read-side swizzle term

    // ln(2cosh(x/2)) - ln2 = t/8 - t^2/192 + t^3/2880 - 17t^4/645120, t=x^2
    constexpr float C1 = 0.125f, C2 = -5.2083333e-3f, C3 = 3.4722222e-4f, C4 = -2.6354832e-5f;
    float sh = 0.f, sx = 0.f;

    for (int nt = 0; nt < NT; ++nt) {
        f32x4 acc[4][4] = {};
#pragma unroll
        for (int ks = 0; ks < KS; ++ks) {
            const int cur = ks & 1;                     // KS even -> parity aligns
            if (ks < KS - 1)       stageB(cur ^ 1, nt, (ks + 1) * BK);
            else if (nt < NT - 1)  stageB(cur ^ 1, nt + 1, 0);
            bf16x8 bfr[4];
#pragma unroll
            for (int j = 0; j < 4; ++j) {
                const int row = brow + j * 16;
                const int g = (lane >> 4) ^ rg;
                bfr[j] = *(const bf16x8*)&sB[cur][row * BK + g * 8];
            }
#pragma unroll
            for (int m = 0; m < 4; ++m)
#pragma unroll
                for (int j = 0; j < 4; ++j)
                    acc[m][j] = __builtin_amdgcn_mfma_f32_16x16x32_bf16(a[m][ks], bfr[j], acc[m][j], 0, 0, 0);
            __syncthreads();
        }
        // Per-tile epilogue (per-wave VALU only).
        // C/D layout: col=lane&15, row=(lane>>4)*4+reg (m89-verified).
        const int c0 = cbase + nt * BN + wc * 64 + (lane & 15);
        int cid_r[4];
#pragma unroll
        for (int j = 0; j < 4; ++j) cid_r[j] = cids[c0 + j * 16];
#pragma unroll
        for (int m = 0; m < 4; ++m)
#pragma unroll
            for (int j = 0; j < 4; ++j)
#pragma unroll
                for (int r = 0; r < 4; ++r) {
                    const float x = acc[m][j][r];
                    const float t2 = x * x;
                    float q = __builtin_fmaf(t2, C4, C3);
                    q = __builtin_fmaf(t2, q, C2);
                    q = __builtin_fmaf(t2, q, C1);
                    sh = __builtin_fmaf(t2, q, sh);
                    const float cc = (pid_r[m * 4 + r] == cid_r[j]) ? -0.5f : 0.5f;
                    sx = __builtin_fmaf(x, cc, sx);
                }
    }

    float lsum = sh + sx;
#pragma unroll
    for (int off = 32; off; off >>= 1) lsum += __shfl_xor(lsum, off, 64);
    __shared__ float wsum[4];
    if (lane == 0) wsum[wv] = lsum;
    __syncthreads();
    if (tid == 0) partial[blockIdx.y * gridDim.x + blockIdx.x] = wsum[0] + wsum[1] + wsum[2] + wsum[3];
}

// Deterministic final reduction over 512 block partials; adds folded ln2.
__global__ __launch_bounds__(256) void reduce_kernel(const float* __restrict__ part,
                                                     float* __restrict__ out) {
    const int tid = threadIdx.x;
    double s = 0.0;
    for (int i = tid; i < 512; i += 256) s += (double)part[i];
#pragma unroll
    for (int off = 32; off; off >>= 1) s += __shfl_xor(s, off, 64);
    __shared__ double red[4];
    const int lane = tid & 63, wv = tid >> 6;
    if (lane == 0) red[wv] = s;
    __syncthreads();
    if (tid == 0)
        out[0] = (float)((red[0] + red[1] + red[2] + red[3]) * (1.0 / ((double)P * (double)C))
                         + 0.69314718055994531);
}

extern "C" void kernel_launch(void* const* d_in, const int* in_sizes, int n_in,
                              void* d_out, int out_size, void* d_ws, size_t ws_size,
                              hipStream_t stream) {
    const float* prev_feat = (const float*)d_in[0];
    const float* cur_feat  = (const float*)d_in[1];
    const int* prev_ids    = (const int*)d_in[2];
    const int* cur_ids     = (const int*)d_in[3];
    float* out = (float*)d_out;

    char* ws = (char*)d_ws;
    unsigned short* prevb = (unsigned short*)ws;                          // 4 MB
    unsigned short* curb  = (unsigned short*)(ws + (size_t)P * D * 2);    // 4 MB
    float* partial = (float*)(ws + (size_t)(P + C) * D * 2);              // 2 KB

    prep_kernel<<<(P + C) / 4, 256, 0, stream>>>(prev_feat, cur_feat, prevb, curb);
    dim3 grid(C / (BN * NT), P / BM);                                     // 8 x 64
    gemm_bce_kernel<<<grid, 256, 0, stream>>>(prevb, curb, prev_ids, cur_ids, partial);
    reduce_kernel<<<1, 256, 0, stream>>>(partial, out);
}

// Round 4
// 59.947 us; speedup vs baseline: 1.3078x; 1.0167x over previous
//
#include <hip/hip_runtime.h>
#include <hip/hip_bf16.h>

typedef __attribute__((ext_vector_type(8))) short bf16x8;
typedef __attribute__((ext_vector_type(4))) float f32x4;
typedef __attribute__((ext_vector_type(2))) float f32x2;

constexpr int P = 8192, C = 8192, D = 256;
constexpr int BM = 128;   // rows per block (A slab, held in registers)
constexpr int BN = 128;   // cols per N-tile
constexpr int BK = 32;
constexpr int NT = 8;     // N-tiles per block
constexpr int KS = D / BK;  // 8 K-steps per tile; 64 flattened steps

__device__ __forceinline__ void gload_lds16(const void* g, void* l) {
    __builtin_amdgcn_global_load_lds((const __attribute__((address_space(1))) void*)g,
                                     (__attribute__((address_space(3))) void*)l, 16, 0, 0);
}

__device__ __forceinline__ unsigned short bfbits(float f) {
    __hip_bfloat16 h = __float2bfloat16(f);
    return __builtin_bit_cast(unsigned short, h);
}

// Normalize rows to unit L2 norm, store bf16. One wave per row, float4 loads.
__global__ __launch_bounds__(256) void prep_kernel(const float* __restrict__ prev,
                                                   const float* __restrict__ cur,
                                                   unsigned short* __restrict__ prevb,
                                                   unsigned short* __restrict__ curb) {
    const int lane = threadIdx.x & 63;
    const int wv = threadIdx.x >> 6;
    const int row = blockIdx.x * 4 + wv;
    const float* src;
    unsigned short* dst;
    int r;
    if (row < P) { src = prev; dst = prevb; r = row; }
    else         { src = cur;  dst = curb;  r = row - P; }
    const float4 v = *(const float4*)(src + (size_t)r * D + lane * 4);
    float ss = v.x * v.x + v.y * v.y + v.z * v.z + v.w * v.w;
#pragma unroll
    for (int off = 32; off; off >>= 1) ss += __shfl_xor(ss, off, 64);
    const float inv = 1.0f / sqrtf(ss);   // norms ~16; eps=1e-6 unreachable
    ushort4 o;
    o.x = bfbits(v.x * inv);
    o.y = bfbits(v.y * inv);
    o.z = bfbits(v.z * inv);
    o.w = bfbits(v.w * inv);
    *(ushort4*)(dst + (size_t)r * D + lane * 4) = o;
}

// Persistent-A GEMM, counted-vmcnt pipeline (T3-min + T4 + T5):
//  - A slab (128 rows x full K) in registers, 8 N-tiles per block.
//  - B streams through a 3-deep LDS ring, staged 2 steps ahead.
//  - Per step: vmcnt(2) [stage-t landed; t+1,t+2 in flight] -> raw s_barrier
//    -> ds_read buf[t%3] -> stage t+2 -> setprio(1) MFMA x16 setprio(0).
//    No vmcnt(0) drain in the main loop (the m97-ceiling stall).
//  - Race-safe with ONE barrier/step: readers of buf[(t-1)%3] retired their
//    ds_reads (lgkmcnt before MFMA use) before barrier_t; stage t+2 writes it
//    only after barrier_t.
//  - Fused BCE epilogue per tile, packed f32x2 math (v_pk_fma_f32).
__global__ __launch_bounds__(256, 2) void gemm_bce_kernel(
    const unsigned short* __restrict__ Ab, const unsigned short* __restrict__ Bb,
    const int* __restrict__ pids, const int* __restrict__ cids,
    float* __restrict__ partial) {
    __shared__ short sB[3][BN * BK];   // 3 x 8 KB ring

    const int tid = threadIdx.x;
    const int lane = tid & 63;
    const int wv = tid >> 6;
    const int wr = wv >> 1, wc = wv & 1;
    const int pblock = blockIdx.y * BM;
    const int cbase = blockIdx.x * (BN * NT);

    const int kg = (lane >> 4) * 8;       // k-granule offset within a K-step
    const int arow0 = pblock + wr * 64 + (lane & 15);

    // ---- A slab -> registers (held for the whole kernel) ----
    bf16x8 a[4][8];
#pragma unroll
    for (int m = 0; m < 4; ++m)
#pragma unroll
        for (int ks = 0; ks < KS; ++ks)
            a[m][ks] = *(const bf16x8*)(Ab + (size_t)(arow0 + m * 16) * D + ks * BK + kg);

    int pid_r[16];
#pragma unroll
    for (int m = 0; m < 4; ++m)
#pragma unroll
        for (int r = 0; r < 4; ++r)
            pid_r[m * 4 + r] = pids[pblock + wr * 64 + m * 16 + (lane >> 4) * 4 + r];

    // ---- B staging (swizzled source granule; LDS written linearly) ----
    const int srow = lane >> 2;                         // row within 16-row chunk
    const int sg = (lane & 3) ^ ((lane >> 3) & 3);      // inverse-swizzled granule
    auto stageB = [&](int buf, int s) {                 // s = flattened step
        const int ntile = s >> 3;
        const int k0 = (s & 7) * BK;
#pragma unroll
        for (int i = 0; i < 2; ++i) {
            const int q = wv * 2 + i;                   // 8 chunks of 16 rows
            gload_lds16(Bb + (size_t)(cbase + ntile * BN + q * 16 + srow) * D + k0 + sg * 8,
                        &sB[buf][q * 512]);
        }
    };

    stageB(0, 0);
    stageB(1, 1);

    const int brow = wc * 64 + (lane & 15);
    const int rg = ((lane & 15) >> 1) & 3;              // read-side swizzle term
    const int gsel = ((lane >> 4) ^ rg) * 8;

    // ln(2cosh(x/2)) - ln2 = t/8 - t^2/192 + t^3/2880 - 17t^4/645120, t=x^2
    constexpr float C1 = 0.125f, C2 = -5.2083333e-3f, C3 = 3.4722222e-4f, C4 = -2.6354832e-5f;
    f32x2 sh2 = {0.f, 0.f}, sx2 = {0.f, 0.f};

    for (int nt = 0; nt < NT; ++nt) {
        f32x4 acc[4][4] = {};
#pragma unroll
        for (int ks = 0; ks < KS; ++ks) {
            const int t = nt * KS + ks;                 // uniform across block
            if (t == 63) asm volatile("s_waitcnt vmcnt(0)" ::: "memory");
            else         asm volatile("s_waitcnt vmcnt(2)" ::: "memory");
            asm volatile("s_barrier" ::: "memory");
            const int cur = t % 3;
            bf16x8 bfr[4];
#pragma unroll
            for (int j = 0; j < 4; ++j)
                bfr[j] = *(const bf16x8*)&sB[cur][(brow + j * 16) * BK + gsel];
            if (t < 62) stageB((t + 2) % 3, t + 2);
            __builtin_amdgcn_s_setprio(1);
#pragma unroll
            for (int m = 0; m < 4; ++m)
#pragma unroll
                for (int j = 0; j < 4; ++j)
                    acc[m][j] = __builtin_amdgcn_mfma_f32_16x16x32_bf16(a[m][ks], bfr[j], acc[m][j], 0, 0, 0);
            __builtin_amdgcn_s_setprio(0);
        }
        // Per-tile fused BCE epilogue (per-wave VALU, packed f32x2, no barrier).
        // C/D layout: col=lane&15, row=(lane>>4)*4+reg (m89-verified).
        const int c0 = cbase + nt * BN + wc * 64 + (lane & 15);
        int cid_r[4];
#pragma unroll
        for (int j = 0; j < 4; ++j) cid_r[j] = cids[c0 + j * 16];
#pragma unroll
        for (int m = 0; m < 4; ++m)
#pragma unroll
            for (int j = 0; j < 4; ++j)
#pragma unroll
                for (int rp = 0; rp < 2; ++rp) {
                    const f32x2 x = {acc[m][j][rp * 2], acc[m][j][rp * 2 + 1]};
                    const f32x2 t2 = x * x;
                    f32x2 q = t2 * C4 + C3;
                    q = t2 * q + C2;
                    q = t2 * q + C1;
                    sh2 = t2 * q + sh2;
                    const f32x2 cc = {
                        (pid_r[m * 4 + rp * 2]     == cid_r[j]) ? -0.5f : 0.5f,
                        (pid_r[m * 4 + rp * 2 + 1] == cid_r[j]) ? -0.5f : 0.5f};
                    sx2 = x * cc + sx2;
                }
    }

    float lsum = sh2.x + sh2.y + sx2.x + sx2.y;
#pragma unroll
    for (int off = 32; off; off >>= 1) lsum += __shfl_xor(lsum, off, 64);
    __shared__ float wsum[4];
    if (lane == 0) wsum[wv] = lsum;
    __syncthreads();
    if (tid == 0) partial[blockIdx.y * gridDim.x + blockIdx.x] = wsum[0] + wsum[1] + wsum[2] + wsum[3];
}

// Deterministic final reduction over 512 block partials; adds folded ln2.
__global__ __launch_bounds__(256) void reduce_kernel(const float* __restrict__ part,
                                                     float* __restrict__ out) {
    const int tid = threadIdx.x;
    double s = 0.0;
    for (int i = tid; i < 512; i += 256) s += (double)part[i];
#pragma unroll
    for (int off = 32; off; off >>= 1) s += __shfl_xor(s, off, 64);
    __shared__ double red[4];
    const int lane = tid & 63, wv = tid >> 6;
    if (lane == 0) red[wv] = s;
    __syncthreads();
    if (tid == 0)
        out[0] = (float)((red[0] + red[1] + red[2] + red[3]) * (1.0 / ((double)P * (double)C))
                         + 0.69314718055994531);
}

extern "C" void kernel_launch(void* const* d_in, const int* in_sizes, int n_in,
                              void* d_out, int out_size, void* d_ws, size_t ws_size,
                              hipStream_t stream) {
    const float* prev_feat = (const float*)d_in[0];
    const float* cur_feat  = (const float*)d_in[1];
    const int* prev_ids    = (const int*)d_in[2];
    const int* cur_ids     = (const int*)d_in[3];
    float* out = (float*)d_out;

    char* ws = (char*)d_ws;
    unsigned short* prevb = (unsigned short*)ws;                          // 4 MB
    unsigned short* curb  = (unsigned short*)(ws + (size_t)P * D * 2);    // 4 MB
    float* partial = (float*)(ws + (size_t)(P + C) * D * 2);              // 2 KB

    prep_kernel<<<(P + C) / 4, 256, 0, stream>>>(prev_feat, cur_feat, prevb, curb);
    dim3 grid(C / (BN * NT), P / BM);                                     // 8 x 64
    gemm_bce_kernel<<<grid, 256, 0, stream>>>(prevb, curb, prev_ids, cur_ids, partial);
    reduce_kernel<<<1, 256, 0, stream>>>(partial, out);
}

// Round 5
// 58.905 us; speedup vs baseline: 1.3310x; 1.0177x over previous
//
#include <hip/hip_runtime.h>
#include <hip/hip_bf16.h>

typedef __attribute__((ext_vector_type(8))) short bf16x8;
typedef __attribute__((ext_vector_type(4))) float f32x4;
typedef __attribute__((ext_vector_type(2))) float f32x2;

constexpr int P = 8192, C = 8192, D = 256;
constexpr int BM = 128;   // rows per block (A slab, held in registers)
constexpr int BN = 128;   // cols per N-tile
constexpr int BK = 32;
constexpr int NT = 8;     // N-tiles per block
constexpr int KS = D / BK;  // 8 K-steps per tile; 64 flattened steps

__device__ __forceinline__ void gload_lds16(const void* g, void* l) {
    __builtin_amdgcn_global_load_lds((const __attribute__((address_space(1))) void*)g,
                                     (__attribute__((address_space(3))) void*)l, 16, 0, 0);
}

__device__ __forceinline__ unsigned short bfbits(float f) {
    __hip_bfloat16 h = __float2bfloat16(f);
    return __builtin_bit_cast(unsigned short, h);
}

// Normalize rows to unit L2 norm, store bf16. One wave per row, float4 loads.
__global__ __launch_bounds__(256) void prep_kernel(const float* __restrict__ prev,
                                                   const float* __restrict__ cur,
                                                   unsigned short* __restrict__ prevb,
                                                   unsigned short* __restrict__ curb) {
    const int lane = threadIdx.x & 63;
    const int wv = threadIdx.x >> 6;
    const int row = blockIdx.x * 4 + wv;
    const float* src;
    unsigned short* dst;
    int r;
    if (row < P) { src = prev; dst = prevb; r = row; }
    else         { src = cur;  dst = curb;  r = row - P; }
    const float4 v = *(const float4*)(src + (size_t)r * D + lane * 4);
    float ss = v.x * v.x + v.y * v.y + v.z * v.z + v.w * v.w;
#pragma unroll
    for (int off = 32; off; off >>= 1) ss += __shfl_xor(ss, off, 64);
    const float inv = 1.0f / sqrtf(ss);   // norms ~16; eps=1e-6 unreachable
    ushort4 o;
    o.x = bfbits(v.x * inv);
    o.y = bfbits(v.y * inv);
    o.z = bfbits(v.z * inv);
    o.w = bfbits(v.w * inv);
    *(ushort4*)(dst + (size_t)r * D + lane * 4) = o;
}

// Persistent-A GEMM, counted-vmcnt pipeline. Register budget is the whole
// game: A slab 128 VGPR + acc 64 + pid 8 + transients ~= 236. waves_per_eu
// pinned to (2,2) so regalloc gets the full 256-VGPR budget instead of
// capping at 128 and spilling to scratch (round-4 failure: WRITE_SIZE 7.2MB
// of spill traffic, occupancy 5.7 waves/CU).
__global__ __attribute__((amdgpu_flat_work_group_size(256, 256), amdgpu_waves_per_eu(2, 2)))
void gemm_bce_kernel(
    const unsigned short* __restrict__ Ab, const unsigned short* __restrict__ Bb,
    const int* __restrict__ pids, const int* __restrict__ cids,
    float* __restrict__ partial) {
    __shared__ short sB[3][BN * BK];   // 3 x 8 KB ring

    const int tid = threadIdx.x;
    const int lane = tid & 63;
    const int wv = tid >> 6;
    const int wr = wv >> 1, wc = wv & 1;
    const int pblock = blockIdx.y * BM;
    const int cbase = blockIdx.x * (BN * NT);

    const int kg = (lane >> 4) * 8;       // k-granule offset within a K-step
    const int arow0 = pblock + wr * 64 + (lane & 15);

    // ---- A slab -> registers (held for the whole kernel): 128 VGPR ----
    bf16x8 a[4][8];
#pragma unroll
    for (int m = 0; m < 4; ++m)
#pragma unroll
        for (int ks = 0; ks < KS; ++ks)
            a[m][ks] = *(const bf16x8*)(Ab + (size_t)(arow0 + m * 16) * D + ks * BK + kg);

    // pids packed 2-per-VGPR (ids < 16384), paired to match the f32x2 epilogue.
    int pidp[8];
#pragma unroll
    for (int m = 0; m < 4; ++m)
#pragma unroll
        for (int rp = 0; rp < 2; ++rp) {
            const int base = pblock + wr * 64 + m * 16 + (lane >> 4) * 4 + rp * 2;
            pidp[m * 2 + rp] = (pids[base] & 0xffff) | (pids[base + 1] << 16);
        }

    // ---- B staging (swizzled source granule; LDS written linearly) ----
    const int srow = lane >> 2;                         // row within 16-row chunk
    const int sg = (lane & 3) ^ ((lane >> 3) & 3);      // inverse-swizzled granule
    auto stageB = [&](int buf, int s) {                 // s = flattened step
        const int ntile = s >> 3;
        const int k0 = (s & 7) * BK;
#pragma unroll
        for (int i = 0; i < 2; ++i) {
            const int q = wv * 2 + i;                   // 8 chunks of 16 rows
            gload_lds16(Bb + (size_t)(cbase + ntile * BN + q * 16 + srow) * D + k0 + sg * 8,
                        &sB[buf][q * 512]);
        }
    };

    stageB(0, 0);
    stageB(1, 1);

    const int brow = wc * 64 + (lane & 15);
    const int rg = ((lane & 15) >> 1) & 3;              // read-side swizzle term
    const int gsel = ((lane >> 4) ^ rg) * 8;

    // ln(2cosh(x/2)) - ln2 = t/8 - t^2/192 + t^3/2880 - 17t^4/645120, t=x^2
    constexpr float C1 = 0.125f, C2 = -5.2083333e-3f, C3 = 3.4722222e-4f, C4 = -2.6354832e-5f;
    f32x2 sh2 = {0.f, 0.f}, sx2 = {0.f, 0.f};

    for (int nt = 0; nt < NT; ++nt) {
        f32x4 acc[4][4] = {};
#pragma unroll
        for (int ks = 0; ks < KS; ++ks) {
            const int t = nt * KS + ks;                 // uniform across block
            if (t == 63) asm volatile("s_waitcnt vmcnt(0)" ::: "memory");
            else         asm volatile("s_waitcnt vmcnt(2)" ::: "memory");
            asm volatile("s_barrier" ::: "memory");
            const int cur = t % 3;
            bf16x8 bfr[4];
#pragma unroll
            for (int j = 0; j < 4; ++j)
                bfr[j] = *(const bf16x8*)&sB[cur][(brow + j * 16) * BK + gsel];
            if (t < 62) stageB((t + 2) % 3, t + 2);
            __builtin_amdgcn_s_setprio(1);
#pragma unroll
            for (int m = 0; m < 4; ++m)
#pragma unroll
                for (int j = 0; j < 4; ++j)
                    acc[m][j] = __builtin_amdgcn_mfma_f32_16x16x32_bf16(a[m][ks], bfr[j], acc[m][j], 0, 0, 0);
            __builtin_amdgcn_s_setprio(0);
        }
        // Per-tile fused BCE epilogue (per-wave VALU, packed f32x2, no barrier).
        // C/D layout: col=lane&15, row=(lane>>4)*4+reg (m89-verified).
        const int c0 = cbase + nt * BN + wc * 64 + (lane & 15);
        int cid_r[4];
#pragma unroll
        for (int j = 0; j < 4; ++j) cid_r[j] = cids[c0 + j * 16];
#pragma unroll
        for (int m = 0; m < 4; ++m)
#pragma unroll
            for (int j = 0; j < 4; ++j)
#pragma unroll
                for (int rp = 0; rp < 2; ++rp) {
                    const f32x2 x = {acc[m][j][rp * 2], acc[m][j][rp * 2 + 1]};
                    const f32x2 t2 = x * x;
                    f32x2 q = t2 * C4 + C3;
                    q = t2 * q + C2;
                    q = t2 * q + C1;
                    sh2 = t2 * q + sh2;
                    const int pp = pidp[m * 2 + rp];
                    const f32x2 cc = {
                        ((pp & 0xffff) == cid_r[j]) ? -0.5f : 0.5f,
                        ((pp >> 16)    == cid_r[j]) ? -0.5f : 0.5f};
                    sx2 = x * cc + sx2;
                }
    }

    float lsum = sh2.x + sh2.y + sx2.x + sx2.y;
#pragma unroll
    for (int off = 32; off; off >>= 1) lsum += __shfl_xor(lsum, off, 64);
    __shared__ float wsum[4];
    if (lane == 0) wsum[wv] = lsum;
    __syncthreads();
    if (tid == 0) partial[blockIdx.y * gridDim.x + blockIdx.x] = wsum[0] + wsum[1] + wsum[2] + wsum[3];
}

// Deterministic final reduction over 512 block partials; adds folded ln2.
__global__ __launch_bounds__(256) void reduce_kernel(const float* __restrict__ part,
                                                     float* __restrict__ out) {
    const int tid = threadIdx.x;
    double s = 0.0;
    for (int i = tid; i < 512; i += 256) s += (double)part[i];
#pragma unroll
    for (int off = 32; off; off >>= 1) s += __shfl_xor(s, off, 64);
    __shared__ double red[4];
    const int lane = tid & 63, wv = tid >> 6;
    if (lane == 0) red[wv] = s;
    __syncthreads();
    if (tid == 0)
        out[0] = (float)((red[0] + red[1] + red[2] + red[3]) * (1.0 / ((double)P * (double)C))
                         + 0.69314718055994531);
}

extern "C" void kernel_launch(void* const* d_in, const int* in_sizes, int n_in,
                              void* d_out, int out_size, void* d_ws, size_t ws_size,
                              hipStream_t stream) {
    const float* prev_feat = (const float*)d_in[0];
    const float* cur_feat  = (const float*)d_in[1];
    const int* prev_ids    = (const int*)d_in[2];
    const int* cur_ids     = (const int*)d_in[3];
    float* out = (float*)d_out;

    char* ws = (char*)d_ws;
    unsigned short* prevb = (unsigned short*)ws;                          // 4 MB
    unsigned short* curb  = (unsigned short*)(ws + (size_t)P * D * 2);    // 4 MB
    float* partial = (float*)(ws + (size_t)(P + C) * D * 2);              // 2 KB

    prep_kernel<<<(P + C) / 4, 256, 0, stream>>>(prev_feat, cur_feat, prevb, curb);
    dim3 grid(C / (BN * NT), P / BM);                                     // 8 x 64
    gemm_bce_kernel<<<grid, 256, 0, stream>>>(prevb, curb, prev_ids, cur_ids, partial);
    reduce_kernel<<<1, 256, 0, stream>>>(partial, out);
}

// Round 6
// 55.140 us; speedup vs baseline: 1.4219x; 1.0683x over previous
//
#include <hip/hip_runtime.h>
#include <hip/hip_bf16.h>

typedef __attribute__((ext_vector_type(8))) short bf16x8;
typedef __attribute__((ext_vector_type(4))) float f32x4;
typedef __attribute__((ext_vector_type(2))) float f32x2;

constexpr int P = 8192, C = 8192, D = 256;
constexpr int BM = 128;     // block rows (A slab in registers)
constexpr int BNT = 64;     // cols per N-tile
constexpr int NT = 16;      // N-tiles per block -> 1024 cols/block
constexpr int STEPS = NT * 4;  // 64 steps of BK=64

__device__ __forceinline__ void gload_lds16(const void* g, void* l) {
    __builtin_amdgcn_global_load_lds((const __attribute__((address_space(1))) void*)g,
                                     (__attribute__((address_space(3))) void*)l, 16, 0, 0);
}

__device__ __forceinline__ unsigned short bfbits(float f) {
    __hip_bfloat16 h = __float2bfloat16(f);
    return __builtin_bit_cast(unsigned short, h);
}

// Normalize rows to unit L2 norm, store bf16. One wave per row, float4 loads.
__global__ __launch_bounds__(256) void prep_kernel(const float* __restrict__ prev,
                                                   const float* __restrict__ cur,
                                                   unsigned short* __restrict__ prevb,
                                                   unsigned short* __restrict__ curb) {
    const int lane = threadIdx.x & 63;
    const int wv = threadIdx.x >> 6;
    const int row = blockIdx.x * 4 + wv;
    const float* src;
    unsigned short* dst;
    int r;
    if (row < P) { src = prev; dst = prevb; r = row; }
    else         { src = cur;  dst = curb;  r = row - P; }
    const float4 v = *(const float4*)(src + (size_t)r * D + lane * 4);
    float ss = v.x * v.x + v.y * v.y + v.z * v.z + v.w * v.w;
#pragma unroll
    for (int off = 32; off; off >>= 1) ss += __shfl_xor(ss, off, 64);
    const float inv = 1.0f / sqrtf(ss);   // norms ~16; eps=1e-6 unreachable
    ushort4 o;
    o.x = bfbits(v.x * inv);
    o.y = bfbits(v.y * inv);
    o.z = bfbits(v.z * inv);
    o.w = bfbits(v.w * inv);
    *(ushort4*)(dst + (size_t)r * D + lane * 4) = o;
}

// Persistent-A GEMM, counted-vmcnt ring pipeline.
// Register budget by construction: A slab a[4][8]=128 + acc[4][2]=32 +
// bfr 16 + pid 8 + misc ~20 ~= 204 < 256 (2 waves/EU) -> no spill (the
// r4/r5 failure was ~270 demand -> scratch traffic in the K-loop).
// Main loop has NO vmem except staging (cids pre-copied to LDS), so the
// hand-counted vmcnt(2) is exact. 4 waves (2M x 2N), wave tile 64x32,
// BK=64/step (16 MFMA, 4 ds_read_b128, 2 global_load_lds per wave/step).
__global__ __attribute__((amdgpu_flat_work_group_size(256, 256), amdgpu_waves_per_eu(2, 2)))
void gemm_bce_kernel(
    const unsigned short* __restrict__ Ab, const unsigned short* __restrict__ Bb,
    const int* __restrict__ pids, const int* __restrict__ cids,
    float* __restrict__ partial) {
    __shared__ short sB[3][BNT * 64];   // 3 x 8 KB ring (64 cols x 64 k)
    __shared__ int cid_lds[BNT * NT];   // 4 KB: this block's cur_ids slice
    __shared__ float wsum[4];

    const int tid = threadIdx.x;
    const int lane = tid & 63;
    const int wv = tid >> 6;
    const int wr = wv >> 1, wc = wv & 1;
    const int pblock = blockIdx.y * BM;
    const int cbase = blockIdx.x * (BNT * NT);

    // ---- B staging: source granule pre-swizzled (g ^= row&7), LDS linear ----
    const int gsrc = (lane & 7) ^ (lane >> 3);
    auto stageB = [&](int buf, int s) {                 // s = flattened step
        const size_t colbase = (size_t)(cbase + (s >> 2) * BNT + wv * 16 + (lane >> 3));
        const int k0 = (s & 3) * 64;
#pragma unroll
        for (int i = 0; i < 2; ++i)
            gload_lds16(Bb + (colbase + i * 8) * D + k0 + gsrc * 8,
                        &sB[buf][wv * 1024 + i * 512]);
    };

    stageB(0, 0);
    stageB(1, 1);

    // ---- prologue loads (latency hidden behind staging) ----
    const int kg = (lane >> 4) * 8;
    const int arow0 = pblock + wr * 64 + (lane & 15);
    bf16x8 a[4][8];                       // full-K A slab: 128 VGPR
#pragma unroll
    for (int m = 0; m < 4; ++m)
#pragma unroll
        for (int kk = 0; kk < 8; ++kk)
            a[m][kk] = *(const bf16x8*)(Ab + (size_t)(arow0 + m * 16) * D + kk * 32 + kg);

    int pidp[8];                          // pids packed 2/VGPR (ids < 16384)
#pragma unroll
    for (int m = 0; m < 4; ++m)
#pragma unroll
        for (int rp = 0; rp < 2; ++rp) {
            const int base = pblock + wr * 64 + m * 16 + (lane >> 4) * 4 + rp * 2;
            pidp[m * 2 + rp] = (pids[base] & 0xffff) | (pids[base + 1] << 16);
        }

    *(int4*)&cid_lds[tid * 4] = *(const int4*)&cids[cbase + tid * 4];

    __syncthreads();   // drains prologue stages + publishes cid_lds (once)

    // ln(2cosh(x/2)) - ln2 = t/8 - t^2/192 + t^3/2880 - 17t^4/645120, t=x^2
    constexpr float C1 = 0.125f, C2 = -5.2083333e-3f, C3 = 3.4722222e-4f, C4 = -2.6354832e-5f;
    f32x2 sh2 = {0.f, 0.f}, sx2 = {0.f, 0.f};

    const int brow = wc * 32 + (lane & 15);
    int cur = 0;

    for (int nt = 0; nt < NT; ++nt) {
        f32x4 acc[4][2] = {};
#pragma unroll
        for (int k4 = 0; k4 < 4; ++k4) {
            const int t = nt * 4 + k4;                  // uniform across block
            if (t == STEPS - 1) asm volatile("s_waitcnt vmcnt(0)" ::: "memory");
            else                asm volatile("s_waitcnt vmcnt(2)" ::: "memory");
            asm volatile("s_barrier" ::: "memory");
            bf16x8 bfr[2][2];
#pragma unroll
            for (int ks = 0; ks < 2; ++ks)
#pragma unroll
                for (int j = 0; j < 2; ++j) {
                    const int gp = ((ks * 4 + (lane >> 4)) ^ (lane & 7)) * 8;
                    bfr[ks][j] = *(const bf16x8*)&sB[cur][(brow + j * 16) * 64 + gp];
                }
            if (t < STEPS - 2) stageB(cur >= 1 ? cur - 1 : 2, t + 2);
            __builtin_amdgcn_s_setprio(1);
#pragma unroll
            for (int ks = 0; ks < 2; ++ks)
#pragma unroll
                for (int m = 0; m < 4; ++m)
#pragma unroll
                    for (int j = 0; j < 2; ++j)
                        acc[m][j] = __builtin_amdgcn_mfma_f32_16x16x32_bf16(
                            a[m][k4 * 2 + ks], bfr[ks][j], acc[m][j], 0, 0, 0);
            __builtin_amdgcn_s_setprio(0);
            cur = (cur == 2) ? 0 : cur + 1;
        }
        // Per-tile fused BCE epilogue (VALU + LDS only; no vmem, no barrier).
        // C/D layout: col=lane&15, row=(lane>>4)*4+reg (m89-verified).
        int cid_r[2];
#pragma unroll
        for (int j = 0; j < 2; ++j)
            cid_r[j] = cid_lds[nt * BNT + wc * 32 + j * 16 + (lane & 15)];
#pragma unroll
        for (int m = 0; m < 4; ++m)
#pragma unroll
            for (int j = 0; j < 2; ++j)
#pragma unroll
                for (int rp = 0; rp < 2; ++rp) {
                    const f32x2 x = {acc[m][j][rp * 2], acc[m][j][rp * 2 + 1]};
                    const f32x2 t2 = x * x;
                    f32x2 q = t2 * C4 + C3;
                    q = t2 * q + C2;
                    q = t2 * q + C1;
                    sh2 = t2 * q + sh2;
                    const int pp = pidp[m * 2 + rp];
                    const f32x2 cc = {
                        ((pp & 0xffff) == cid_r[j]) ? -0.5f : 0.5f,
                        ((pp >> 16)    == cid_r[j]) ? -0.5f : 0.5f};
                    sx2 = x * cc + sx2;
                }
    }

    float lsum = sh2.x + sh2.y + sx2.x + sx2.y;
#pragma unroll
    for (int off = 32; off; off >>= 1) lsum += __shfl_xor(lsum, off, 64);
    if (lane == 0) wsum[wv] = lsum;
    __syncthreads();
    if (tid == 0) partial[blockIdx.y * gridDim.x + blockIdx.x] = wsum[0] + wsum[1] + wsum[2] + wsum[3];
}

// Deterministic final reduction over 512 block partials; adds folded ln2.
__global__ __launch_bounds__(256) void reduce_kernel(const float* __restrict__ part,
                                                     float* __restrict__ out) {
    const int tid = threadIdx.x;
    double s = 0.0;
    for (int i = tid; i < 512; i += 256) s += (double)part[i];
#pragma unroll
    for (int off = 32; off; off >>= 1) s += __shfl_xor(s, off, 64);
    __shared__ double red[4];
    const int lane = tid & 63, wv = tid >> 6;
    if (lane == 0) red[wv] = s;
    __syncthreads();
    if (tid == 0)
        out[0] = (float)((red[0] + red[1] + red[2] + red[3]) * (1.0 / ((double)P * (double)C))
                         + 0.69314718055994531);
}

extern "C" void kernel_launch(void* const* d_in, const int* in_sizes, int n_in,
                              void* d_out, int out_size, void* d_ws, size_t ws_size,
                              hipStream_t stream) {
    const float* prev_feat = (const float*)d_in[0];
    const float* cur_feat  = (const float*)d_in[1];
    const int* prev_ids    = (const int*)d_in[2];
    const int* cur_ids     = (const int*)d_in[3];
    float* out = (float*)d_out;

    char* ws = (char*)d_ws;
    unsigned short* prevb = (unsigned short*)ws;                          // 4 MB
    unsigned short* curb  = (unsigned short*)(ws + (size_t)P * D * 2);    // 4 MB
    float* partial = (float*)(ws + (size_t)(P + C) * D * 2);              // 2 KB

    prep_kernel<<<(P + C) / 4, 256, 0, stream>>>(prev_feat, cur_feat, prevb, curb);
    dim3 grid(C / (BNT * NT), P / BM);                                    // 8 x 64
    gemm_bce_kernel<<<grid, 256, 0, stream>>>(prevb, curb, prev_ids, cur_ids, partial);
    reduce_kernel<<<1, 256, 0, stream>>>(partial, out);
}

// Round 7
// 54.225 us; speedup vs baseline: 1.4459x; 1.0169x over previous
//
#include <hip/hip_runtime.h>
#include <hip/hip_bf16.h>

typedef __attribute__((ext_vector_type(8))) short bf16x8;
typedef __attribute__((ext_vector_type(4))) float f32x4;
typedef __attribute__((ext_vector_type(2))) float f32x2;

constexpr int P = 8192, C = 8192, D = 256;
constexpr int BM = 128;     // block rows = 4 waves x 32
constexpr int BNT = 32;     // cols per N-tile
constexpr int NT = 16;      // tiles per block -> 512 cols
constexpr int STEPS = NT * 4;  // 64 steps of BK=64

__device__ __forceinline__ void gload_lds16(const void* g, void* l) {
    __builtin_amdgcn_global_load_lds((const __attribute__((address_space(1))) void*)g,
                                     (__attribute__((address_space(3))) void*)l, 16, 0, 0);
}

__device__ __forceinline__ unsigned short bfbits(float f) {
    __hip_bfloat16 h = __float2bfloat16(f);
    return __builtin_bit_cast(unsigned short, h);
}

// Normalize rows to unit L2 norm, store bf16. One wave per row, float4 loads.
__global__ __launch_bounds__(256) void prep_kernel(const float* __restrict__ prev,
                                                   const float* __restrict__ cur,
                                                   unsigned short* __restrict__ prevb,
                                                   unsigned short* __restrict__ curb) {
    const int lane = threadIdx.x & 63;
    const int wv = threadIdx.x >> 6;
    const int row = blockIdx.x * 4 + wv;
    const float* src;
    unsigned short* dst;
    int r;
    if (row < P) { src = prev; dst = prevb; r = row; }
    else         { src = cur;  dst = curb;  r = row - P; }
    const float4 v = *(const float4*)(src + (size_t)r * D + lane * 4);
    float ss = v.x * v.x + v.y * v.y + v.z * v.z + v.w * v.w;
#pragma unroll
    for (int off = 32; off; off >>= 1) ss += __shfl_xor(ss, off, 64);
    const float inv = 1.0f / sqrtf(ss);   // norms ~16; eps=1e-6 unreachable
    ushort4 o;
    o.x = bfbits(v.x * inv);
    o.y = bfbits(v.y * inv);
    o.z = bfbits(v.z * inv);
    o.w = bfbits(v.w * inv);
    *(ushort4*)(dst + (size_t)r * D + lane * 4) = o;
}

// Persistent-A GEMM tuned for OCCUPANCY: wave tile 32x32 keeps unified regs
// ~120 (a[2][8]=64 + acc 16 + bfr 16 + misc) -> waves_per_eu(4,4) admits
// 4 waves/SIMD = 4 blocks/CU, one wave per block per SIMD: four independent
// barrier domains anti-phase to hide LDS/L2 latency (r6 failure: 240-reg
// waves -> 2 waves/SIMD -> 73% idle despite counted-vmcnt pipeline).
// 4-deep LDS ring, staged 3 ahead, vmcnt(2); tile order rotated per block
// to de-correlate same-slice L2 line requests.
__global__ __attribute__((amdgpu_flat_work_group_size(256, 256), amdgpu_waves_per_eu(4, 4)))
void gemm_bce_kernel(
    const unsigned short* __restrict__ Ab, const unsigned short* __restrict__ Bb,
    const int* __restrict__ pids, const int* __restrict__ cids,
    float* __restrict__ partial) {
    __shared__ short sB[4][BNT * 64];   // 4 x 4 KB ring (32 cols x 64 k)
    __shared__ int cid_lds[BNT * NT];   // 2 KB
    __shared__ float wsum[4];

    const int tid = threadIdx.x;
    const int lane = tid & 63;
    const int wv = tid >> 6;
    const int pblock = blockIdx.y * BM;
    const int cbase = blockIdx.x * (BNT * NT);
    const int phase = blockIdx.y & 15;

    // ---- B staging: thread t owns col=t>>3, phys granule t&7 of the 32x64
    // tile; source granule pre-swizzled (g ^= col&7), LDS written linearly ----
    const int scol = tid >> 3;
    const int sgran = (tid & 7) ^ (scol & 7);
    auto stageB = [&](int u) {                           // u = sequence step
        const int tl = ((u >> 2) + phase) & 15;
        const int k0 = (u & 3) * 64;
        gload_lds16(Bb + (size_t)(cbase + tl * BNT + scol) * D + k0 + sgran * 8,
                    &sB[u & 3][wv * 512]);
    };

    stageB(0);
    stageB(1);
    stageB(2);

    // ---- prologue loads (latency overlapped with staging) ----
    const int kg = (lane >> 4) * 8;
    const int arow0 = pblock + wv * 32 + (lane & 15);
    bf16x8 a[2][8];                       // full-K A slab: 64 regs
#pragma unroll
    for (int m = 0; m < 2; ++m)
#pragma unroll
        for (int kk = 0; kk < 8; ++kk)
            a[m][kk] = *(const bf16x8*)(Ab + (size_t)(arow0 + m * 16) * D + kk * 32 + kg);

    int pidp[4];                          // pids packed 2/VGPR (ids < 16384)
#pragma unroll
    for (int m = 0; m < 2; ++m)
#pragma unroll
        for (int rp = 0; rp < 2; ++rp) {
            const int base = pblock + wv * 32 + m * 16 + (lane >> 4) * 4 + rp * 2;
            pidp[m * 2 + rp] = (pids[base] & 0xffff) | (pids[base + 1] << 16);
        }

    *(int2*)&cid_lds[tid * 2] = *(const int2*)&cids[cbase + tid * 2];

    __syncthreads();   // drains prologue stages + publishes cid_lds (once)

    // ln(2cosh(x/2)) - ln2 = t/8 - t^2/192 + t^3/2880 - 17t^4/645120, t=x^2
    constexpr float C1 = 0.125f, C2 = -5.2083333e-3f, C3 = 3.4722222e-4f, C4 = -2.6354832e-5f;
    f32x2 sh2 = {0.f, 0.f}, sx2 = {0.f, 0.f};

    for (int tt = 0; tt < NT; ++tt) {
        const int tl = (tt + phase) & 15;               // rotated tile index
        f32x4 acc[2][2] = {};
#pragma unroll
        for (int k4 = 0; k4 < 4; ++k4) {
            const int u = tt * 4 + k4;                  // uniform across block
            if (u < STEPS - 2)       asm volatile("s_waitcnt vmcnt(2)" ::: "memory");
            else if (u == STEPS - 2) asm volatile("s_waitcnt vmcnt(1)" ::: "memory");
            else                     asm volatile("s_waitcnt vmcnt(0)" ::: "memory");
            asm volatile("s_barrier" ::: "memory");
            const short* sb = &sB[u & 3][0];
            bf16x8 bfr[2][2];
#pragma unroll
            for (int ks = 0; ks < 2; ++ks)
#pragma unroll
                for (int j = 0; j < 2; ++j) {
                    const int col = j * 16 + (lane & 15);
                    const int pg = (ks * 4 + (lane >> 4)) ^ (lane & 7);
                    bfr[ks][j] = *(const bf16x8*)&sb[col * 64 + pg * 8];
                }
            if (u < STEPS - 3) stageB(u + 3);
            __builtin_amdgcn_s_setprio(1);
#pragma unroll
            for (int ks = 0; ks < 2; ++ks)
#pragma unroll
                for (int m = 0; m < 2; ++m)
#pragma unroll
                    for (int j = 0; j < 2; ++j)
                        acc[m][j] = __builtin_amdgcn_mfma_f32_16x16x32_bf16(
                            a[m][k4 * 2 + ks], bfr[ks][j], acc[m][j], 0, 0, 0);
            __builtin_amdgcn_s_setprio(0);
        }
        // Per-tile fused BCE epilogue (VALU + LDS only; no vmem, no barrier).
        // C/D layout: col=lane&15, row=(lane>>4)*4+reg (m89-verified).
        int cid_r[2];
#pragma unroll
        for (int j = 0; j < 2; ++j)
            cid_r[j] = cid_lds[tl * BNT + j * 16 + (lane & 15)];
#pragma unroll
        for (int m = 0; m < 2; ++m)
#pragma unroll
            for (int j = 0; j < 2; ++j)
#pragma unroll
                for (int rp = 0; rp < 2; ++rp) {
                    const f32x2 x = {acc[m][j][rp * 2], acc[m][j][rp * 2 + 1]};
                    const f32x2 t2 = x * x;
                    f32x2 q = t2 * C4 + C3;
                    q = t2 * q + C2;
                    q = t2 * q + C1;
                    sh2 = t2 * q + sh2;
                    const int pp = pidp[m * 2 + rp];
                    const f32x2 cc = {
                        ((pp & 0xffff) == cid_r[j]) ? -0.5f : 0.5f,
                        ((pp >> 16)    == cid_r[j]) ? -0.5f : 0.5f};
                    sx2 = x * cc + sx2;
                }
    }

    float lsum = sh2.x + sh2.y + sx2.x + sx2.y;
#pragma unroll
    for (int off = 32; off; off >>= 1) lsum += __shfl_xor(lsum, off, 64);
    if (lane == 0) wsum[wv] = lsum;
    __syncthreads();
    if (tid == 0) partial[blockIdx.y * gridDim.x + blockIdx.x] = wsum[0] + wsum[1] + wsum[2] + wsum[3];
}

// Deterministic final reduction over 1024 block partials; adds folded ln2.
__global__ __launch_bounds__(256) void reduce_kernel(const float* __restrict__ part,
                                                     float* __restrict__ out) {
    const int tid = threadIdx.x;
    double s = 0.0;
    for (int i = tid; i < 1024; i += 256) s += (double)part[i];
#pragma unroll
    for (int off = 32; off; off >>= 1) s += __shfl_xor(s, off, 64);
    __shared__ double red[4];
    const int lane = tid & 63, wv = tid >> 6;
    if (lane == 0) red[wv] = s;
    __syncthreads();
    if (tid == 0)
        out[0] = (float)((red[0] + red[1] + red[2] + red[3]) * (1.0 / ((double)P * (double)C))
                         + 0.69314718055994531);
}

extern "C" void kernel_launch(void* const* d_in, const int* in_sizes, int n_in,
                              void* d_out, int out_size, void* d_ws, size_t ws_size,
                              hipStream_t stream) {
    const float* prev_feat = (const float*)d_in[0];
    const float* cur_feat  = (const float*)d_in[1];
    const int* prev_ids    = (const int*)d_in[2];
    const int* cur_ids     = (const int*)d_in[3];
    float* out = (float*)d_out;

    char* ws = (char*)d_ws;
    unsigned short* prevb = (unsigned short*)ws;                          // 4 MB
    unsigned short* curb  = (unsigned short*)(ws + (size_t)P * D * 2);    // 4 MB
    float* partial = (float*)(ws + (size_t)(P + C) * D * 2);              // 4 KB

    prep_kernel<<<(P + C) / 4, 256, 0, stream>>>(prev_feat, cur_feat, prevb, curb);
    dim3 grid(C / (BNT * NT), P / BM);                                    // 16 x 64
    gemm_bce_kernel<<<grid, 256, 0, stream>>>(prevb, curb, prev_ids, cur_ids, partial);
    reduce_kernel<<<1, 256, 0, stream>>>(partial, out);
}